// Round 5
// baseline (300.954 us; speedup 1.0000x reference)
//
#include <hip/hip_runtime.h>
#include <hip/hip_bf16.h>
#include <hip/hip_fp16.h>

// Problem constants (from reference file)
#define N_USERS 50000
#define N_NODES 100000
#define N_EDGES 1600000
#define DIM 128
#define CAP 64            // per-row bucket capacity (max degree ~45 for Poisson(16))

// fused-kernel role layout: in the first 2048 blocks, every 4th block is gemm
// (512 gemm blocks interleaved with 1536 fill blocks -> co-resident from t=0);
// remaining blocks are fill. Each fill block covers 1024 edges (4 per thread).
#define GEMM_BLOCKS 512
#define FILL_BLOCKS ((N_EDGES + 1023) / 1024)          // 1563
#define FUSED_GRID (2048 + (FILL_BLOCKS - 1536))       // 2075

typedef __attribute__((ext_vector_type(8))) _Float16 half8;
typedef __attribute__((ext_vector_type(4))) _Float16 half4;
typedef __attribute__((ext_vector_type(4))) float f32x4;

// ---------------- zero counts ----------------
__global__ void zero_counts_kernel(int* __restrict__ counts) {
    int i = blockIdx.x * blockDim.x + threadIdx.x;   // 25000 threads, int4 each
    if (i < N_NODES / 4) ((int4*)counts)[i] = (int4){0, 0, 0, 0};
}

// ---------------- gemm body (shared by fused + fallback kernels) ----------
// One wave computes a 16-row x 128-col output stripe using 8 col-tiles of
// 16x16x32 f16 MFMA, K=128 in 4 steps. W pre-swizzled into B-fragment order
// in LDS so each B operand is a single ds_read_b128.
// A-fragment: lane holds A[m=lane&15][k=(lane>>4)*8+j]; C/D: col=lane&15,
// row=(lane>>4)*4+reg   [verified mapping, learn_hip m89]
__device__ __forceinline__ void gemm_body(
        const float* __restrict__ u_f, const float* __restrict__ v_f,
        const float* __restrict__ W, _Float16* __restrict__ node_f,
        _Float16* wfrag, int blockId, int nBlocks) {
    const int tid = threadIdx.x;

    // Build W fragments: element (t,s,lane,j) = W[s*32+(lane>>4)*8+j][t*16+(lane&15)]
    for (int f = tid * 64, end = tid * 64 + 64; f < end; ++f) {
        const int ts   = f >> 9;        // 0..31
        const int rem  = f & 511;
        const int ln   = rem >> 3;      // 0..63
        const int j    = rem & 7;
        const int t    = ts >> 2;
        const int s    = ts & 3;
        const int krow = s * 32 + (ln >> 4) * 8 + j;
        const int col  = t * 16 + (ln & 15);
        wfrag[f] = (_Float16)W[krow * DIM + col];
    }
    __syncthreads();

    const int lane = tid & 63;
    const int wave = tid >> 6;
    const int m    = lane & 15;
    const int quad = lane >> 4;
    const int n_wtiles = N_NODES / 16;  // 6250 (exact)

    for (int wt = blockId * 4 + wave; wt < n_wtiles; wt += nBlocks * 4) {
        const int row = wt * 16 + m;
        const float* src = (row < N_USERS) ? u_f + (size_t)row * DIM
                                           : v_f + (size_t)(row - N_USERS) * DIM;
        f32x4 acc[8];
        #pragma unroll
        for (int t = 0; t < 8; ++t) acc[t] = (f32x4){0.f, 0.f, 0.f, 0.f};

        #pragma unroll
        for (int s = 0; s < 4; ++s) {
            const float* ap = src + s * 32 + quad * 8;
            const float4 a0 = *(const float4*)ap;
            const float4 a1 = *(const float4*)(ap + 4);
            half8 af;
            af[0] = (_Float16)a0.x; af[1] = (_Float16)a0.y;
            af[2] = (_Float16)a0.z; af[3] = (_Float16)a0.w;
            af[4] = (_Float16)a1.x; af[5] = (_Float16)a1.y;
            af[6] = (_Float16)a1.z; af[7] = (_Float16)a1.w;
            #pragma unroll
            for (int t = 0; t < 8; ++t) {
                const half8 wf = *(const half8*)&wfrag[((t * 4 + s) * 64 + lane) * 8];
                acc[t] = __builtin_amdgcn_mfma_f32_16x16x32_f16(af, wf, acc[t], 0, 0, 0);
            }
        }

        const int base = wt * 16;
        #pragma unroll
        for (int t = 0; t < 8; ++t) {
            #pragma unroll
            for (int r = 0; r < 4; ++r) {
                const int orow = base + quad * 4 + r;
                node_f[(size_t)orow * DIM + t * 16 + m] = (_Float16)acc[t][r];
            }
        }
    }
}

// ---------------- fused: gemm + bucket fill (role-interleaved) -------------
__global__ __launch_bounds__(256) void fused_gemm_fill_kernel(
        const float* __restrict__ u_f, const float* __restrict__ v_f,
        const float* __restrict__ W, _Float16* __restrict__ node_f,
        const int* __restrict__ rows, const int* __restrict__ cols,
        const float* __restrict__ vals,
        int* __restrict__ counts, long long* __restrict__ buckets) {
    __shared__ _Float16 wfrag[32 * 64 * 8];   // 32 KB (unused by fill blocks)
    const int b = blockIdx.x;
    const int q = b >> 2, rbit = b & 3;

    if (b < 2048 && rbit == 0) {
        gemm_body(u_f, v_f, W, node_f, wfrag, q, GEMM_BLOCKS);
        return;
    }
    // fill role: 4 independent edges per thread (4 atomics in flight)
    const int fid = (b < 2048) ? (q * 3 + rbit - 1) : (1536 + b - 2048);
    const int ebase = fid * 1024 + threadIdx.x;
    #pragma unroll
    for (int k = 0; k < 4; ++k) {
        const int e = ebase + k * 256;
        if (e < N_EDGES) {
            const int r = rows[e];
            const int slot = atomicAdd(&counts[r], 1);
            if (slot < CAP) {
                const long long packed =
                    ((long long)__float_as_int(vals[e]) << 32) | (unsigned)cols[e];
                __builtin_nontemporal_store(packed, &buckets[(size_t)r * CAP + slot]);
            }
        }
    }
}

// standalone gemm for the fallback path
__global__ __launch_bounds__(256) void gemm_mfma_kernel(
        const float* __restrict__ u_f, const float* __restrict__ v_f,
        const float* __restrict__ W, _Float16* __restrict__ node_f) {
    __shared__ _Float16 wfrag[32 * 64 * 8];
    gemm_body(u_f, v_f, W, node_f, wfrag, blockIdx.x, gridDim.x);
}

// ---------------- gather: one wave per output row, pair-wise edges --------
// lanes 0..31 serve edge j, lanes 32..63 serve edge j+1 (per-lane shfl src);
// each lane loads 4 f16 (8B) of its edge's node_f row. Final shfl_xor(32)
// merges the two half-wave partial sums. 8-edge unroll -> 4 loads in flight.
__global__ __launch_bounds__(256) void gather_kernel(
        const _Float16* __restrict__ node_f, const int* __restrict__ counts,
        const long long* __restrict__ buckets, float* __restrict__ out) {
    const int row  = (blockIdx.x * blockDim.x + threadIdx.x) >> 6;
    const int lane = threadIdx.x & 63;
    if (row >= N_NODES) return;
    const int pid = lane >> 5;          // which edge of the pair
    const int cl  = lane & 31;          // col-group: cols [cl*4, cl*4+4)

    int cnt = counts[row];
    if (cnt > CAP) cnt = CAP;

    int   col = 0;
    float val = 0.f;
    if (lane < cnt) {
        const long long p =
            __builtin_nontemporal_load(&buckets[(size_t)row * CAP + lane]);
        col = (int)(unsigned)p;
        val = __int_as_float((int)(p >> 32));
    }

    f32x4 acc = {0.f, 0.f, 0.f, 0.f};
    int j = 0;
    for (; j + 8 <= cnt; j += 8) {                 // wave-uniform trip count
        int c[4]; float v[4]; half4 h[4];
        #pragma unroll
        for (int p = 0; p < 4; ++p) {
            c[p] = __shfl(col, j + 2 * p + pid, 64);
            v[p] = __shfl(val, j + 2 * p + pid, 64);
        }
        #pragma unroll
        for (int p = 0; p < 4; ++p)
            h[p] = *(const half4*)&node_f[(size_t)c[p] * DIM + cl * 4];
        #pragma unroll
        for (int p = 0; p < 4; ++p) {
            acc[0] += v[p] * (float)h[p][0];
            acc[1] += v[p] * (float)h[p][1];
            acc[2] += v[p] * (float)h[p][2];
            acc[3] += v[p] * (float)h[p][3];
        }
    }
    for (; j + 2 <= cnt; j += 2) {
        const int   c = __shfl(col, j + pid, 64);
        const float v = __shfl(val, j + pid, 64);
        const half4 h = *(const half4*)&node_f[(size_t)c * DIM + cl * 4];
        acc[0] += v * (float)h[0];
        acc[1] += v * (float)h[1];
        acc[2] += v * (float)h[2];
        acc[3] += v * (float)h[3];
    }
    if (j < cnt) {                                  // odd edge: lower half only
        const int   c = __shfl(col, j, 64);
        const float vv = __shfl(val, j, 64);
        const float v = pid ? 0.f : vv;
        const half4 h = *(const half4*)&node_f[(size_t)c * DIM + cl * 4];
        acc[0] += v * (float)h[0];
        acc[1] += v * (float)h[1];
        acc[2] += v * (float)h[2];
        acc[3] += v * (float)h[3];
    }

    // merge half-wave partials
    #pragma unroll
    for (int i = 0; i < 4; ++i) acc[i] += __shfl_xor(acc[i], 32, 64);

    if (pid == 0) {                                 // lanes 0..31 store 16B
        f32x4 r;
        r[0] = acc[0] > 0.f ? acc[0] : 0.f;         // fused relu
        r[1] = acc[1] > 0.f ? acc[1] : 0.f;
        r[2] = acc[2] > 0.f ? acc[2] : 0.f;
        r[3] = acc[3] > 0.f ? acc[3] : 0.f;
        __builtin_nontemporal_store(r, (f32x4*)&out[(size_t)row * DIM + cl * 4]);
    }
}

// ---------------- fallback path (small workspace): atomic scatter ----------
__global__ void zero_out_kernel(float* __restrict__ out) {
    int i = blockIdx.x * blockDim.x + threadIdx.x;
    int idx = i * 4;
    if (idx < N_NODES * DIM) {
        float4 z = {0.f, 0.f, 0.f, 0.f};
        *(float4*)&out[idx] = z;
    }
}

__global__ void scatter_kernel(const _Float16* __restrict__ node_f,
                               const int* __restrict__ rows, const int* __restrict__ cols,
                               const float* __restrict__ vals, float* __restrict__ out) {
    int t = blockIdx.x * blockDim.x + threadIdx.x;
    int e = t >> 5;             // 32 threads per edge, 4 elems each
    int part = t & 31;
    if (e >= N_EDGES) return;
    int r = rows[e], c = cols[e];
    float v = vals[e];
    const __half2 h0 = *(const __half2*)&node_f[(size_t)c * DIM + part * 4];
    const __half2 h1 = *(const __half2*)&node_f[(size_t)c * DIM + part * 4 + 2];
    const float2 f0 = __half22float2(h0);
    const float2 f1 = __half22float2(h1);
    float* dst = &out[(size_t)r * DIM + part * 4];
    unsafeAtomicAdd(dst + 0, v * f0.x);
    unsafeAtomicAdd(dst + 1, v * f0.y);
    unsafeAtomicAdd(dst + 2, v * f1.x);
    unsafeAtomicAdd(dst + 3, v * f1.y);
}

__global__ void relu_kernel(float* __restrict__ out) {
    int i = blockIdx.x * blockDim.x + threadIdx.x;
    int idx = i * 4;
    if (idx < N_NODES * DIM) {
        float4 v = *(float4*)&out[idx];
        v.x = v.x > 0.f ? v.x : 0.f;
        v.y = v.y > 0.f ? v.y : 0.f;
        v.z = v.z > 0.f ? v.z : 0.f;
        v.w = v.w > 0.f ? v.w : 0.f;
        *(float4*)&out[idx] = v;
    }
}

extern "C" void kernel_launch(void* const* d_in, const int* in_sizes, int n_in,
                              void* d_out, int out_size, void* d_ws, size_t ws_size,
                              hipStream_t stream) {
    const float* u_f  = (const float*)d_in[0];
    const float* v_f  = (const float*)d_in[1];
    const int*   rows = (const int*)d_in[2];
    const int*   cols = (const int*)d_in[3];
    const float* vals = (const float*)d_in[4];
    const float* W    = (const float*)d_in[5];
    float* out = (float*)d_out;

    char* ws = (char*)d_ws;
    const size_t nodef_bytes  = (size_t)N_NODES * DIM * 2;   // 25,600,000 (f16)
    const size_t counts_bytes = (size_t)N_NODES * 4;         //    400,000
    const size_t bucket_bytes = (size_t)N_NODES * CAP * 8;   // 51,200,000

    _Float16* node_f = (_Float16*)ws;
    int* counts = (int*)(ws + nodef_bytes);
    long long* buckets = (long long*)(ws + nodef_bytes + counts_bytes);

    if (ws_size >= nodef_bytes + counts_bytes + bucket_bytes) {
        zero_counts_kernel<<<(N_NODES / 4 + 255) / 256, 256, 0, stream>>>(counts);
        fused_gemm_fill_kernel<<<FUSED_GRID, 256, 0, stream>>>(
            u_f, v_f, W, node_f, rows, cols, vals, counts, buckets);
        gather_kernel<<<(N_NODES * 64 + 255) / 256, 256, 0, stream>>>(
            node_f, counts, buckets, out);
    } else {
        // fallback: atomic scatter
        gemm_mfma_kernel<<<512, 256, 0, stream>>>(u_f, v_f, W, node_f);
        zero_out_kernel<<<(N_NODES * DIM / 4 + 255) / 256, 256, 0, stream>>>(out);
        scatter_kernel<<<((size_t)N_EDGES * 32 + 255) / 256, 256, 0, stream>>>(
            node_f, rows, cols, vals, out);
        relu_kernel<<<(N_NODES * DIM / 4 + 255) / 256, 256, 0, stream>>>(out);
    }
}

// Round 6
// 265.916 us; speedup vs baseline: 1.1318x; 1.1318x over previous
//
#include <hip/hip_runtime.h>
#include <hip/hip_bf16.h>
#include <hip/hip_fp16.h>

// Problem constants (from reference file)
#define N_USERS 50000
#define N_NODES 100000
#define N_EDGES 1600000
#define DIM 128
#define CAP 64            // per-row bucket capacity (max degree ~45 for Poisson(16))

// fused kernel: blocks 0..511 do the MFMA gemm, blocks 512.. do bucket fill,
// 1 edge per thread (fill is atomic-latency-bound: thread count == MLP; the
// R5 4-edges/thread variant regressed 113->160us).
#define GEMM_BLOCKS 512
#define FILL_BLOCKS (N_EDGES / 256)            // 6250, exact
#define FUSED_GRID (GEMM_BLOCKS + FILL_BLOCKS)

typedef __attribute__((ext_vector_type(8))) _Float16 half8;
typedef __attribute__((ext_vector_type(4))) _Float16 half4;
typedef __attribute__((ext_vector_type(4))) float f32x4;

// ---------------- zero counts ----------------
__global__ void zero_counts_kernel(int* __restrict__ counts) {
    int i = blockIdx.x * blockDim.x + threadIdx.x;   // 25000 threads, int4 each
    if (i < N_NODES / 4) ((int4*)counts)[i] = (int4){0, 0, 0, 0};
}

// ---------------- gemm body (shared by fused + fallback kernels) ----------
// One wave computes a 16-row x 128-col output stripe using 8 col-tiles of
// 16x16x32 f16 MFMA, K=128 in 4 steps. W pre-swizzled into B-fragment order
// in LDS so each B operand is a single ds_read_b128.
// A-fragment: lane holds A[m=lane&15][k=(lane>>4)*8+j]; C/D: col=lane&15,
// row=(lane>>4)*4+reg   [verified mapping, learn_hip m89]
__device__ __forceinline__ void gemm_body(
        const float* __restrict__ u_f, const float* __restrict__ v_f,
        const float* __restrict__ W, _Float16* __restrict__ node_f,
        _Float16* wfrag, int blockId, int nBlocks) {
    const int tid = threadIdx.x;

    // Build W fragments: element (t,s,lane,j) = W[s*32+(lane>>4)*8+j][t*16+(lane&15)]
    for (int f = tid * 64, end = tid * 64 + 64; f < end; ++f) {
        const int ts   = f >> 9;        // 0..31
        const int rem  = f & 511;
        const int ln   = rem >> 3;      // 0..63
        const int j    = rem & 7;
        const int t    = ts >> 2;
        const int s    = ts & 3;
        const int krow = s * 32 + (ln >> 4) * 8 + j;
        const int col  = t * 16 + (ln & 15);
        wfrag[f] = (_Float16)W[krow * DIM + col];
    }
    __syncthreads();

    const int lane = tid & 63;
    const int wave = tid >> 6;
    const int m    = lane & 15;
    const int quad = lane >> 4;
    const int n_wtiles = N_NODES / 16;  // 6250 (exact)

    for (int wt = blockId * 4 + wave; wt < n_wtiles; wt += nBlocks * 4) {
        const int row = wt * 16 + m;
        const float* src = (row < N_USERS) ? u_f + (size_t)row * DIM
                                           : v_f + (size_t)(row - N_USERS) * DIM;
        f32x4 acc[8];
        #pragma unroll
        for (int t = 0; t < 8; ++t) acc[t] = (f32x4){0.f, 0.f, 0.f, 0.f};

        #pragma unroll
        for (int s = 0; s < 4; ++s) {
            const float* ap = src + s * 32 + quad * 8;
            const float4 a0 = *(const float4*)ap;
            const float4 a1 = *(const float4*)(ap + 4);
            half8 af;
            af[0] = (_Float16)a0.x; af[1] = (_Float16)a0.y;
            af[2] = (_Float16)a0.z; af[3] = (_Float16)a0.w;
            af[4] = (_Float16)a1.x; af[5] = (_Float16)a1.y;
            af[6] = (_Float16)a1.z; af[7] = (_Float16)a1.w;
            #pragma unroll
            for (int t = 0; t < 8; ++t) {
                const half8 wf = *(const half8*)&wfrag[((t * 4 + s) * 64 + lane) * 8];
                acc[t] = __builtin_amdgcn_mfma_f32_16x16x32_f16(af, wf, acc[t], 0, 0, 0);
            }
        }

        const int base = wt * 16;
        #pragma unroll
        for (int t = 0; t < 8; ++t) {
            #pragma unroll
            for (int r = 0; r < 4; ++r) {
                const int orow = base + quad * 4 + r;
                node_f[(size_t)orow * DIM + t * 16 + m] = (_Float16)acc[t][r];
            }
        }
    }
}

// ---------------- fused: gemm (blocks 0..511) + bucket fill ----------------
// gemm and fill are data-independent; fusing lets fill's latency-bound
// scattered atomics hide the gemm (single stream => no overlap otherwise).
__global__ __launch_bounds__(256) void fused_gemm_fill_kernel(
        const float* __restrict__ u_f, const float* __restrict__ v_f,
        const float* __restrict__ W, _Float16* __restrict__ node_f,
        const int* __restrict__ rows, const int* __restrict__ cols,
        const float* __restrict__ vals,
        int* __restrict__ counts, long long* __restrict__ buckets) {
    __shared__ _Float16 wfrag[32 * 64 * 8];   // 32 KB (unused by fill blocks)
    if (blockIdx.x < GEMM_BLOCKS) {
        gemm_body(u_f, v_f, W, node_f, wfrag, blockIdx.x, GEMM_BLOCKS);
        return;
    }
    const int e = (blockIdx.x - GEMM_BLOCKS) * 256 + threadIdx.x;  // < N_EDGES exact
    const int r = rows[e];
    const int slot = atomicAdd(&counts[r], 1);
    if (slot < CAP) {
        const long long packed =
            ((long long)__float_as_int(vals[e]) << 32) | (unsigned)cols[e];
        buckets[(size_t)r * CAP + slot] = packed;   // plain store: let L2 merge
    }
}

// standalone gemm for the fallback path
__global__ __launch_bounds__(256) void gemm_mfma_kernel(
        const float* __restrict__ u_f, const float* __restrict__ v_f,
        const float* __restrict__ W, _Float16* __restrict__ node_f) {
    __shared__ _Float16 wfrag[32 * 64 * 8];
    gemm_body(u_f, v_f, W, node_f, wfrag, blockIdx.x, gridDim.x);
}

// ---------------- gather: one wave per output row, pair-wise edges --------
// lanes 0..31 serve edge j, lanes 32..63 serve edge j+1 (per-lane shfl src);
// each lane loads 4 f16 (8B) of its edge's node_f row. Final shfl_xor(32)
// merges the two half-wave partials. 8-edge unroll -> 4 loads in flight.
__global__ __launch_bounds__(256) void gather_kernel(
        const _Float16* __restrict__ node_f, const int* __restrict__ counts,
        const long long* __restrict__ buckets, float* __restrict__ out) {
    const int row  = (blockIdx.x * blockDim.x + threadIdx.x) >> 6;
    const int lane = threadIdx.x & 63;
    if (row >= N_NODES) return;
    const int pid = lane >> 5;          // which edge of the pair
    const int cl  = lane & 31;          // col-group: cols [cl*4, cl*4+4)

    int cnt = counts[row];
    if (cnt > CAP) cnt = CAP;

    int   col = 0;
    float val = 0.f;
    if (lane < cnt) {
        const long long p = buckets[(size_t)row * CAP + lane];  // coalesced 512B/wave
        col = (int)(unsigned)p;
        val = __int_as_float((int)(p >> 32));
    }

    f32x4 acc = {0.f, 0.f, 0.f, 0.f};
    int j = 0;
    for (; j + 8 <= cnt; j += 8) {                 // wave-uniform trip count
        int c[4]; float v[4]; half4 h[4];
        #pragma unroll
        for (int p = 0; p < 4; ++p) {
            c[p] = __shfl(col, j + 2 * p + pid, 64);
            v[p] = __shfl(val, j + 2 * p + pid, 64);
        }
        #pragma unroll
        for (int p = 0; p < 4; ++p)
            h[p] = *(const half4*)&node_f[(size_t)c[p] * DIM + cl * 4];
        #pragma unroll
        for (int p = 0; p < 4; ++p) {
            acc[0] += v[p] * (float)h[p][0];
            acc[1] += v[p] * (float)h[p][1];
            acc[2] += v[p] * (float)h[p][2];
            acc[3] += v[p] * (float)h[p][3];
        }
    }
    for (; j + 2 <= cnt; j += 2) {
        const int   c = __shfl(col, j + pid, 64);
        const float v = __shfl(val, j + pid, 64);
        const half4 h = *(const half4*)&node_f[(size_t)c * DIM + cl * 4];
        acc[0] += v * (float)h[0];
        acc[1] += v * (float)h[1];
        acc[2] += v * (float)h[2];
        acc[3] += v * (float)h[3];
    }
    if (j < cnt) {                                  // odd edge: lower half only
        const int   c = __shfl(col, j, 64);
        const float vv = __shfl(val, j, 64);
        const float v = pid ? 0.f : vv;
        const half4 h = *(const half4*)&node_f[(size_t)c * DIM + cl * 4];
        acc[0] += v * (float)h[0];
        acc[1] += v * (float)h[1];
        acc[2] += v * (float)h[2];
        acc[3] += v * (float)h[3];
    }

    // merge half-wave partials
    #pragma unroll
    for (int i = 0; i < 4; ++i) acc[i] += __shfl_xor(acc[i], 32, 64);

    if (pid == 0) {                                 // lanes 0..31 store 16B
        f32x4 r;
        r[0] = acc[0] > 0.f ? acc[0] : 0.f;         // fused relu
        r[1] = acc[1] > 0.f ? acc[1] : 0.f;
        r[2] = acc[2] > 0.f ? acc[2] : 0.f;
        r[3] = acc[3] > 0.f ? acc[3] : 0.f;
        // nt store: out is never re-read; keep 50MB out of L2
        __builtin_nontemporal_store(r, (f32x4*)&out[(size_t)row * DIM + cl * 4]);
    }
}

// ---------------- fallback path (small workspace): atomic scatter ----------
__global__ void zero_out_kernel(float* __restrict__ out) {
    int i = blockIdx.x * blockDim.x + threadIdx.x;
    int idx = i * 4;
    if (idx < N_NODES * DIM) {
        float4 z = {0.f, 0.f, 0.f, 0.f};
        *(float4*)&out[idx] = z;
    }
}

__global__ void scatter_kernel(const _Float16* __restrict__ node_f,
                               const int* __restrict__ rows, const int* __restrict__ cols,
                               const float* __restrict__ vals, float* __restrict__ out) {
    int t = blockIdx.x * blockDim.x + threadIdx.x;
    int e = t >> 5;             // 32 threads per edge, 4 elems each
    int part = t & 31;
    if (e >= N_EDGES) return;
    int r = rows[e], c = cols[e];
    float v = vals[e];
    const __half2 h0 = *(const __half2*)&node_f[(size_t)c * DIM + part * 4];
    const __half2 h1 = *(const __half2*)&node_f[(size_t)c * DIM + part * 4 + 2];
    const float2 f0 = __half22float2(h0);
    const float2 f1 = __half22float2(h1);
    float* dst = &out[(size_t)r * DIM + part * 4];
    unsafeAtomicAdd(dst + 0, v * f0.x);
    unsafeAtomicAdd(dst + 1, v * f0.y);
    unsafeAtomicAdd(dst + 2, v * f1.x);
    unsafeAtomicAdd(dst + 3, v * f1.y);
}

__global__ void relu_kernel(float* __restrict__ out) {
    int i = blockIdx.x * blockDim.x + threadIdx.x;
    int idx = i * 4;
    if (idx < N_NODES * DIM) {
        float4 v = *(float4*)&out[idx];
        v.x = v.x > 0.f ? v.x : 0.f;
        v.y = v.y > 0.f ? v.y : 0.f;
        v.z = v.z > 0.f ? v.z : 0.f;
        v.w = v.w > 0.f ? v.w : 0.f;
        *(float4*)&out[idx] = v;
    }
}

extern "C" void kernel_launch(void* const* d_in, const int* in_sizes, int n_in,
                              void* d_out, int out_size, void* d_ws, size_t ws_size,
                              hipStream_t stream) {
    const float* u_f  = (const float*)d_in[0];
    const float* v_f  = (const float*)d_in[1];
    const int*   rows = (const int*)d_in[2];
    const int*   cols = (const int*)d_in[3];
    const float* vals = (const float*)d_in[4];
    const float* W    = (const float*)d_in[5];
    float* out = (float*)d_out;

    char* ws = (char*)d_ws;
    const size_t nodef_bytes  = (size_t)N_NODES * DIM * 2;   // 25,600,000 (f16)
    const size_t counts_bytes = (size_t)N_NODES * 4;         //    400,000
    const size_t bucket_bytes = (size_t)N_NODES * CAP * 8;   // 51,200,000

    _Float16* node_f = (_Float16*)ws;
    int* counts = (int*)(ws + nodef_bytes);
    long long* buckets = (long long*)(ws + nodef_bytes + counts_bytes);

    if (ws_size >= nodef_bytes + counts_bytes + bucket_bytes) {
        zero_counts_kernel<<<(N_NODES / 4 + 255) / 256, 256, 0, stream>>>(counts);
        fused_gemm_fill_kernel<<<FUSED_GRID, 256, 0, stream>>>(
            u_f, v_f, W, node_f, rows, cols, vals, counts, buckets);
        gather_kernel<<<(N_NODES * 64 + 255) / 256, 256, 0, stream>>>(
            node_f, counts, buckets, out);
    } else {
        // fallback: atomic scatter
        gemm_mfma_kernel<<<512, 256, 0, stream>>>(u_f, v_f, W, node_f);
        zero_out_kernel<<<(N_NODES * DIM / 4 + 255) / 256, 256, 0, stream>>>(out);
        scatter_kernel<<<((size_t)N_EDGES * 32 + 255) / 256, 256, 0, stream>>>(
            node_f, rows, cols, vals, out);
        relu_kernel<<<(N_NODES * DIM / 4 + 255) / 256, 256, 0, stream>>>(out);
    }
}